// Round 4
// baseline (22964.526 us; speedup 1.0000x reference)
//
#include <hip/hip_runtime.h>
#include <cmath>

#define NB 128
#define NT 256
#define DEMB 256
#define HH 512
#define NCLS 5
#define PADTOK 29999
#define TC 32          // timestep chunk for xg materialization
#define NBLK 256       // persistent grid (1 block/CU guaranteed co-resident)

typedef __attribute__((ext_vector_type(8))) short bfrag;   // 8 bf16 (4 VGPRs)
typedef __attribute__((ext_vector_type(4))) float faccv;   // 4 fp32 acc

__device__ __forceinline__ unsigned short f2bf(float f) {
  union { float f; unsigned u; } v; v.f = f;
  unsigned r = v.u + 0x7fff + ((v.u >> 16) & 1);   // RNE
  return (unsigned short)(r >> 16);
}
__device__ __forceinline__ float bf2f(unsigned short h) {
  union { unsigned u; float f; } v; v.u = (unsigned)h << 16;
  return v.f;
}
__device__ __forceinline__ float sigf(float x) { return 1.f / (1.f + expf(-x)); }

// ---------------- grid barrier (all NBLK blocks co-resident) ----------------
// Release: fence + per-block slot store. Acquire: poll all slots + fence.
__device__ __forceinline__ void grid_barrier(int* slots, int gen) {
  __syncthreads();
  __threadfence();                         // agent fence: flush block's writes
  if (threadIdx.x == 0)
    __hip_atomic_store(slots + blockIdx.x, gen, __ATOMIC_RELAXED,
                       __HIP_MEMORY_SCOPE_AGENT);
  if (threadIdx.x < 64) {
    int i0 = threadIdx.x;
    for (;;) {
      int v0 = __hip_atomic_load(slots + i0,       __ATOMIC_RELAXED, __HIP_MEMORY_SCOPE_AGENT);
      int v1 = __hip_atomic_load(slots + i0 + 64,  __ATOMIC_RELAXED, __HIP_MEMORY_SCOPE_AGENT);
      int v2 = __hip_atomic_load(slots + i0 + 128, __ATOMIC_RELAXED, __HIP_MEMORY_SCOPE_AGENT);
      int v3 = __hip_atomic_load(slots + i0 + 192, __ATOMIC_RELAXED, __HIP_MEMORY_SCOPE_AGENT);
      if (__all((v0 >= gen) && (v1 >= gen) && (v2 >= gen) && (v3 >= gen))) break;
      __builtin_amdgcn_s_sleep(8);
    }
  }
  __syncthreads();
  __threadfence();                         // acquire: invalidate stale cache
}

// ---------------- fp32 -> bf16 convert ----------------
__global__ __launch_bounds__(256)
void cvt_bf16(const float* __restrict__ src, unsigned short* __restrict__ dst, int n) {
  int i = (blockIdx.x * 256 + threadIdx.x) * 4;
  if (i < n) {
    float4 v = *(const float4*)(src + i);
    dst[i + 0] = f2bf(v.x); dst[i + 1] = f2bf(v.y);
    dst[i + 2] = f2bf(v.z); dst[i + 3] = f2bf(v.w);
  }
}

// ---------------- embedding -> bf16, t-major [T,B,256] ----------------
__global__ __launch_bounds__(64)
void embed_kernel(const int* __restrict__ xw, const float* __restrict__ emb,
                  unsigned short* __restrict__ xe) {
  int bt = blockIdx.x;            // b*T + t
  int b = bt >> 8, t = bt & 255;
  int tok = xw[bt];
  int c = threadIdx.x << 2;
  float4 v = make_float4(0.f, 0.f, 0.f, 0.f);
  if (tok != PADTOK) v = *(const float4*)(emb + (size_t)tok * DEMB + c);
  ushort4 o;
  o.x = f2bf(v.x); o.y = f2bf(v.y); o.z = f2bf(v.z); o.w = f2bf(v.w);
  *(ushort4*)(xe + ((size_t)t * NB + b) * DEMB + c) = o;
}

// ---------------- GEMM tile device fn: C[.,2048] 128x128 tile ----------------
__device__ void gemm_tile(const unsigned short* __restrict__ A, long a_rstride,
                          const unsigned short* __restrict__ W, int K,
                          const float* __restrict__ b1, const float* __restrict__ b2,
                          unsigned short* __restrict__ C,
                          long m0, int n0, unsigned short* lds) {
  unsigned short* At = lds;          // [128][32]
  unsigned short* Bt = lds + 4096;   // [128][32]
  int tid = threadIdx.x;
  int w = tid >> 6, l = tid & 63;
  int q = l >> 4, r16 = l & 15;
  int wm = (w & 1) * 64, wn = (w >> 1) * 64;
  faccv acc[4][4] = {};
  int srow = tid >> 1;
  const unsigned short* Ag = A + (m0 + srow) * a_rstride + (tid & 1) * 8;
  const unsigned short* Wg = W + (long)(n0 + srow) * K + (tid & 1) * 8;

  for (int k0 = 0; k0 < K; k0 += 32) {
    __syncthreads();
    *(float4*)&At[srow * 32 + (tid & 1) * 8]      = *(const float4*)(Ag + k0);
    *(float4*)&At[srow * 32 + (tid & 1) * 8 + 16] = *(const float4*)(Ag + k0 + 16);
    *(float4*)&Bt[srow * 32 + (tid & 1) * 8]      = *(const float4*)(Wg + k0);
    *(float4*)&Bt[srow * 32 + (tid & 1) * 8 + 16] = *(const float4*)(Wg + k0 + 16);
    __syncthreads();
    bfrag af[4], bf[4];
#pragma unroll
    for (int i = 0; i < 4; ++i) {
      af[i] = *(const bfrag*)&At[(wm + i * 16 + r16) * 32 + q * 8];
      bf[i] = *(const bfrag*)&Bt[(wn + i * 16 + r16) * 32 + q * 8];
    }
#pragma unroll
    for (int mf = 0; mf < 4; ++mf)
#pragma unroll
      for (int nf = 0; nf < 4; ++nf)
        acc[mf][nf] = __builtin_amdgcn_mfma_f32_16x16x32_bf16(af[mf], bf[nf], acc[mf][nf], 0, 0, 0);
  }
  __syncthreads();
#pragma unroll
  for (int nf = 0; nf < 4; ++nf) {
    int col = n0 + wn + nf * 16 + r16;
    float bs = b1[col] + b2[col];
#pragma unroll
    for (int mf = 0; mf < 4; ++mf) {
#pragma unroll
      for (int r = 0; r < 4; ++r) {
        long row = m0 + wm + mf * 16 + q * 4 + r;
        C[row * 2048 + col] = f2bf(acc[mf][nf][r] + bs);
      }
    }
  }
}

// ---------------- persistent kernel params ----------------
struct PK {
  const unsigned short *xe;
  const unsigned short *w_ih0f, *w_hh0f, *w_ih0r, *w_hh0r;
  const unsigned short *w_ih1f, *w_hh1f, *w_ih1r;
  const float *bih0f, *bhh0f, *bih0r, *bhh0r, *bih1f, *bhh1f, *bih1r, *bhh1r;
  unsigned short *xgf, *xgr, *xg1r, *h0;
  unsigned short *hf0, *hf1, *hr0, *hr1, *h10, *h11;
  int* slots;
};

// Scan partition (per direction): 16 m-groups (128 gates) x 8 n-groups (16
// batches) = 128 blocks; each wave: m=32 gates (C-rows ordered unit*4+gate),
// n=16 batches, k=512 with whh slice VGPR-resident (32 A-frags = 128 VGPRs).
// Cell state c: 2 fp32 registers per lane, persistent across all 256 steps.
__global__ __launch_bounds__(256, 1)
void persist_kernel(PK P) {
  __shared__ unsigned short lds[8192];   // 16 KB GEMM staging
  const int blk = blockIdx.x, tid = threadIdx.x;
  const int wv = tid >> 6, lane = tid & 63, q = lane >> 4, l16 = lane & 15;
  const size_t XROW = (size_t)NB * DEMB;
  const size_t GROW = (size_t)NB * 2048;
  const size_t HROW = (size_t)NB * 1024;
  int gen = 0;

  // scan identity (valid for both layers; layer1 uses blocks < 128 only)
  const int dir = blk >> 7, b7 = blk & 127;
  const int bn0 = (b7 & 7) * 16;                 // batch group
  const int m0 = (b7 >> 3) * 128 + wv * 32;      // gate-col base for this wave
  const int bb = bn0 + l16;                      // this lane's batch (C col)
  const int gg = l16 & 3, ul = l16 >> 2;         // A-row decode: row16=ul*4+gg
  const int ua0 = (m0 >> 2) + ul;                // A-operand units
  const int ua1 = ((m0 + 16) >> 2) + ul;
  const int ub0 = (m0 >> 2) + q;                 // C-operand units
  const int ub1 = ((m0 + 16) >> 2) + q;

  // ================= layer 0 =================
  {
    const unsigned short* whh = dir ? P.w_hh0r : P.w_hh0f;
    unsigned short* hb[2] = { dir ? P.hr0 : P.hf0, dir ? P.hr1 : P.hf1 };
    float cst0 = 0.f, cst1 = 0.f;

    for (int g = 0; g < 8; ++g) {
      // ---- chunk GEMMs: 512 fwd tiles + 512 rev tiles ----
      for (int t = blk; t < 1024; t += NBLK) {
        bool isr = t >= 512; int tt = t & 511;
        long tm = tt & 31; int tn = tt >> 5;
        const unsigned short* A = P.xe + (size_t)(isr ? (7 - g) : g) * TC * XROW;
        gemm_tile(A, DEMB, isr ? P.w_ih0r : P.w_ih0f, DEMB,
                  isr ? P.bih0r : P.bih0f, isr ? P.bhh0r : P.bhh0f,
                  isr ? P.xgr : P.xgf, tm * 128, tn * 128, lds);
      }
      grid_barrier(P.slots, ++gen);

      // ---- reload VGPR-resident whh slice (cheap: 512 B/lane) ----
      bfrag wA0[16], wA1[16];
      {
        const unsigned short* w0 = whh + ((size_t)(gg * HH + ua0)) * HH + q * 8;
        const unsigned short* w1 = whh + ((size_t)(gg * HH + ua1)) * HH + q * 8;
#pragma unroll
        for (int kc = 0; kc < 16; ++kc) {
          wA0[kc] = *(const bfrag*)(w0 + kc * 32);
          wA1[kc] = *(const bfrag*)(w1 + kc * 32);
        }
      }

      // ---- 32 scan steps ----
      for (int j = 0; j < 32; ++j) {
        int s = g * 32 + j;
        const unsigned short* h_in = hb[s & 1];
        unsigned short* h_out = hb[(s + 1) & 1];
        const unsigned short* xg_t =
            dir ? P.xgr + (size_t)(31 - j) * GROW : P.xgf + (size_t)j * GROW;

        const unsigned short* xr = xg_t + (size_t)bb * 2048;
        faccv a0, a1;
        a0[0] = bf2f(xr[ub0]);            a1[0] = bf2f(xr[ub1]);
        a0[1] = bf2f(xr[HH + ub0]);       a1[1] = bf2f(xr[HH + ub1]);
        a0[2] = bf2f(xr[2 * HH + ub0]);   a1[2] = bf2f(xr[2 * HH + ub1]);
        a0[3] = bf2f(xr[3 * HH + ub0]);   a1[3] = bf2f(xr[3 * HH + ub1]);

        const unsigned short* hr_ = h_in + (size_t)bb * HH + q * 8;
#pragma unroll
        for (int kc = 0; kc < 16; ++kc) {
          bfrag bB = *(const bfrag*)(hr_ + kc * 32);
          a0 = __builtin_amdgcn_mfma_f32_16x16x32_bf16(wA0[kc], bB, a0, 0, 0, 0);
          a1 = __builtin_amdgcn_mfma_f32_16x16x32_bf16(wA1[kc], bB, a1, 0, 0, 0);
        }

        float cn0 = sigf(a0[1]) * cst0 + sigf(a0[0]) * tanhf(a0[2]);
        float hn0 = sigf(a0[3]) * tanhf(cn0); cst0 = cn0;
        float cn1 = sigf(a1[1]) * cst1 + sigf(a1[0]) * tanhf(a1[2]);
        float hn1 = sigf(a1[3]) * tanhf(cn1); cst1 = cn1;

        h_out[(size_t)bb * HH + ub0] = f2bf(hn0);
        h_out[(size_t)bb * HH + ub1] = f2bf(hn1);
        int tt = dir ? (NT - 1 - s) : s;
        unsigned short* hs = P.h0 + (size_t)tt * HROW + (size_t)bb * 1024 + dir * HH;
        hs[ub0] = f2bf(hn0);
        hs[ub1] = f2bf(hn1);

        grid_barrier(P.slots, ++gen);
      }
    }
  }

  // ================= layer 1 (forward scan; blocks < 128) =================
  {
    float cst0 = 0.f, cst1 = 0.f;
    unsigned short* hb[2] = { P.h10, P.h11 };

    for (int g = 0; g < 8; ++g) {
      // ---- chunk GEMM (K=1024) + (chunk 0 only) xg1r tiles ----
      int ntile = (g == 0) ? 528 : 512;
      for (int t = blk; t < ntile; t += NBLK) {
        if (t < 512) {
          long tm = t & 31; int tn = t >> 5;
          gemm_tile(P.h0 + (size_t)g * TC * HROW, 1024, P.w_ih1f, 1024,
                    P.bih1f, P.bhh1f, P.xgf, tm * 128, tn * 128, lds);
        } else {
          int tn = t - 512;
          gemm_tile(P.h0 + (size_t)(NT - 1) * HROW, 1024, P.w_ih1r, 1024,
                    P.bih1r, P.bhh1r, P.xg1r, 0, tn * 128, lds);
        }
      }
      grid_barrier(P.slots, ++gen);

      bfrag wA0[16], wA1[16];
      if (blk < 128) {
        const unsigned short* w0 = P.w_hh1f + ((size_t)(gg * HH + ua0)) * HH + q * 8;
        const unsigned short* w1 = P.w_hh1f + ((size_t)(gg * HH + ua1)) * HH + q * 8;
#pragma unroll
        for (int kc = 0; kc < 16; ++kc) {
          wA0[kc] = *(const bfrag*)(w0 + kc * 32);
          wA1[kc] = *(const bfrag*)(w1 + kc * 32);
        }
      }

      for (int j = 0; j < 32; ++j) {
        if (blk < 128) {
          int s = g * 32 + j;
          const unsigned short* h_in = hb[s & 1];
          unsigned short* h_out = hb[(s + 1) & 1];
          const unsigned short* xr = P.xgf + (size_t)j * GROW + (size_t)bb * 2048;
          faccv a0, a1;
          a0[0] = bf2f(xr[ub0]);            a1[0] = bf2f(xr[ub1]);
          a0[1] = bf2f(xr[HH + ub0]);       a1[1] = bf2f(xr[HH + ub1]);
          a0[2] = bf2f(xr[2 * HH + ub0]);   a1[2] = bf2f(xr[2 * HH + ub1]);
          a0[3] = bf2f(xr[3 * HH + ub0]);   a1[3] = bf2f(xr[3 * HH + ub1]);
          const unsigned short* hr_ = h_in + (size_t)bb * HH + q * 8;
#pragma unroll
          for (int kc = 0; kc < 16; ++kc) {
            bfrag bB = *(const bfrag*)(hr_ + kc * 32);
            a0 = __builtin_amdgcn_mfma_f32_16x16x32_bf16(wA0[kc], bB, a0, 0, 0, 0);
            a1 = __builtin_amdgcn_mfma_f32_16x16x32_bf16(wA1[kc], bB, a1, 0, 0, 0);
          }
          float cn0 = sigf(a0[1]) * cst0 + sigf(a0[0]) * tanhf(a0[2]);
          float hn0 = sigf(a0[3]) * tanhf(cn0); cst0 = cn0;
          float cn1 = sigf(a1[1]) * cst1 + sigf(a1[0]) * tanhf(a1[2]);
          float hn1 = sigf(a1[3]) * tanhf(cn1); cst1 = cn1;
          h_out[(size_t)bb * HH + ub0] = f2bf(hn0);
          h_out[(size_t)bb * HH + ub1] = f2bf(hn1);
        }
        grid_barrier(P.slots, ++gen);
      }
    }
  }
}

// ---------------- layer-1 reverse single step (c_prev = h_prev = 0) ------
__global__ __launch_bounds__(512)
void pw_l1r(const unsigned short* __restrict__ xg, unsigned short* __restrict__ h1r) {
  int b = blockIdx.x, u = threadIdx.x;
  float gi = bf2f(xg[(size_t)b * 2048 + u]);
  float gg = bf2f(xg[(size_t)b * 2048 + 2 * HH + u]);
  float go = bf2f(xg[(size_t)b * 2048 + 3 * HH + u]);
  float cn = sigf(gi) * tanhf(gg);
  h1r[(size_t)b * HH + u] = f2bf(sigf(go) * tanhf(cn));
}

// ---------------- classifier ----------------
__global__ __launch_bounds__(128)
void cls_kernel(const unsigned short* __restrict__ hf, const unsigned short* __restrict__ hr,
                const float* __restrict__ wout, const float* __restrict__ bout,
                float* __restrict__ out) {
  int b = blockIdx.x;
  int tid = threadIdx.x;
  float p[NCLS] = {0.f, 0.f, 0.f, 0.f, 0.f};
  for (int j = tid; j < HH; j += 128) {
    float v = bf2f(hf[(size_t)b * HH + j]);
#pragma unroll
    for (int n = 0; n < NCLS; ++n) p[n] += v * wout[n * (2 * HH) + j];
  }
  for (int j = tid; j < HH; j += 128) {
    float v = bf2f(hr[(size_t)b * HH + j]);
#pragma unroll
    for (int n = 0; n < NCLS; ++n) p[n] += v * wout[n * (2 * HH) + HH + j];
  }
  __shared__ float red[NCLS][128];
  for (int n = 0; n < NCLS; ++n) red[n][tid] = p[n];
  __syncthreads();
  for (int s = 64; s > 0; s >>= 1) {
    if (tid < s)
      for (int n = 0; n < NCLS; ++n) red[n][tid] += red[n][tid + s];
    __syncthreads();
  }
  if (tid == 0)
    for (int n = 0; n < NCLS; ++n) out[b * NCLS + n] = red[n][0] + bout[n];
}

// ---------------- host ----------------
extern "C" void kernel_launch(void* const* d_in, const int* in_sizes, int n_in,
                              void* d_out, int out_size, void* d_ws, size_t ws_size,
                              hipStream_t stream) {
  const int*   xw    = (const int*)  d_in[0];
  const float* emb   = (const float*)d_in[1];
  const float* wih0f = (const float*)d_in[2];
  const float* whh0f = (const float*)d_in[3];
  const float* bih0f = (const float*)d_in[4];
  const float* bhh0f = (const float*)d_in[5];
  const float* wih0r = (const float*)d_in[6];
  const float* whh0r = (const float*)d_in[7];
  const float* bih0r = (const float*)d_in[8];
  const float* bhh0r = (const float*)d_in[9];
  const float* wih1f = (const float*)d_in[10];
  const float* whh1f = (const float*)d_in[11];
  const float* bih1f = (const float*)d_in[12];
  const float* bhh1f = (const float*)d_in[13];
  const float* wih1r = (const float*)d_in[14];
  const float* whh1r = (const float*)d_in[15];
  const float* bih1r = (const float*)d_in[16];
  const float* bhh1r = (const float*)d_in[17];
  const float* wout  = (const float*)d_in[18];
  const float* bout  = (const float*)d_in[19];
  float* out = (float*)d_out;
  (void)whh1r; (void)ws_size;

  // ---- workspace (~128 MB; 163 MB proven safe in round 1) ----
  char* base = (char*)d_ws;
  size_t off = 0;
  auto alloc = [&](size_t bytes) {
    char* p = base + off;
    off += (bytes + 255) & ~(size_t)255;
    return p;
  };
  unsigned short* xe   = (unsigned short*)alloc((size_t)NT * NB * DEMB * 2);
  unsigned short* h0   = (unsigned short*)alloc((size_t)NT * NB * 1024 * 2);
  unsigned short* xgf  = (unsigned short*)alloc((size_t)TC * NB * 2048 * 2);
  unsigned short* xgr  = (unsigned short*)alloc((size_t)TC * NB * 2048 * 2);
  unsigned short* xg1r = (unsigned short*)alloc((size_t)NB * 2048 * 2);
  unsigned short* wb_wih0f = (unsigned short*)alloc(2048 * 256 * 2);
  unsigned short* wb_whh0f = (unsigned short*)alloc(2048 * 512 * 2);
  unsigned short* wb_wih0r = (unsigned short*)alloc(2048 * 256 * 2);
  unsigned short* wb_whh0r = (unsigned short*)alloc(2048 * 512 * 2);
  unsigned short* wb_wih1f = (unsigned short*)alloc(2048 * 1024 * 2);
  unsigned short* wb_wih1r = (unsigned short*)alloc(2048 * 1024 * 2);
  unsigned short* wb_whh1f = (unsigned short*)alloc(2048 * 512 * 2);
  char* stbase = alloc(7 * (size_t)NB * HH * 2 + 1024);
  unsigned short* hf0 = (unsigned short*)stbase;
  unsigned short* hf1 = hf0 + (size_t)NB * HH;
  unsigned short* hr0 = hf1 + (size_t)NB * HH;
  unsigned short* hr1 = hr0 + (size_t)NB * HH;
  unsigned short* h10 = hr1 + (size_t)NB * HH;
  unsigned short* h11 = h10 + (size_t)NB * HH;
  unsigned short* h1r = h11 + (size_t)NB * HH;
  int* slots = (int*)(stbase + 7 * (size_t)NB * HH * 2);

  // zero initial h states + barrier slots
  hipMemsetAsync(stbase, 0, 7 * (size_t)NB * HH * 2 + 1024, stream);

  // ---- weights -> bf16 ----
  auto cvt = [&](const float* s, unsigned short* d, int n) {
    cvt_bf16<<<dim3((n / 4 + 255) / 256), dim3(256), 0, stream>>>(s, d, n);
  };
  cvt(wih0f, wb_wih0f, 2048 * 256);
  cvt(whh0f, wb_whh0f, 2048 * 512);
  cvt(wih0r, wb_wih0r, 2048 * 256);
  cvt(whh0r, wb_whh0r, 2048 * 512);
  cvt(wih1f, wb_wih1f, 2048 * 1024);
  cvt(wih1r, wb_wih1r, 2048 * 1024);
  cvt(whh1f, wb_whh1f, 2048 * 512);

  // ---- embedding (t-major) ----
  embed_kernel<<<dim3(NB * NT), dim3(64), 0, stream>>>(xw, emb, xe);

  // ---- one persistent kernel: all chunk GEMMs + both scans ----
  PK P;
  P.xe = xe;
  P.w_ih0f = wb_wih0f; P.w_hh0f = wb_whh0f;
  P.w_ih0r = wb_wih0r; P.w_hh0r = wb_whh0r;
  P.w_ih1f = wb_wih1f; P.w_hh1f = wb_whh1f; P.w_ih1r = wb_wih1r;
  P.bih0f = bih0f; P.bhh0f = bhh0f; P.bih0r = bih0r; P.bhh0r = bhh0r;
  P.bih1f = bih1f; P.bhh1f = bhh1f; P.bih1r = bih1r; P.bhh1r = bhh1r;
  P.xgf = xgf; P.xgr = xgr; P.xg1r = xg1r; P.h0 = h0;
  P.hf0 = hf0; P.hf1 = hf1; P.hr0 = hr0; P.hr1 = hr1; P.h10 = h10; P.h11 = h11;
  P.slots = slots;
  persist_kernel<<<dim3(NBLK), dim3(256), 0, stream>>>(P);

  // ---- layer-1 reverse single step + classifier ----
  pw_l1r<<<dim3(NB), dim3(512), 0, stream>>>(xg1r, h1r);
  cls_kernel<<<dim3(NB), dim3(128), 0, stream>>>(h10, h1r, wout, bout, out);
}

// Round 6
// 6642.654 us; speedup vs baseline: 3.4571x; 3.4571x over previous
//
#include <hip/hip_runtime.h>
#include <cmath>

#define NB 128
#define NT 256
#define DEMB 256
#define HH 512
#define NCLS 5
#define PADTOK 29999
#define TC 32          // timestep chunk for xg materialization
#define NBLK 256       // persistent grid (1 block/CU co-resident)

typedef __attribute__((ext_vector_type(8))) short bfrag;   // 8 bf16 (4 VGPRs)
typedef __attribute__((ext_vector_type(4))) float faccv;   // 4 fp32 acc
typedef unsigned long long u64;
typedef unsigned int u32;
typedef unsigned short u16;

__device__ __forceinline__ u16 f2bf(float f) {
  union { float f; unsigned u; } v; v.f = f;
  unsigned r = v.u + 0x7fff + ((v.u >> 16) & 1);   // RNE
  return (u16)(r >> 16);
}
__device__ __forceinline__ float bf2f(u16 h) {
  union { unsigned u; float f; } v; v.u = (unsigned)h << 16;
  return v.f;
}
__device__ __forceinline__ float sigf(float x) { return 1.f / (1.f + expf(-x)); }

// ---- coherent (MALL-level) ops: bypass per-XCD L2, NO cache flushes ----
__device__ __forceinline__ void c_st32(u32* p, u32 v) {
  __hip_atomic_store(p, v, __ATOMIC_RELAXED, __HIP_MEMORY_SCOPE_AGENT);
}
__device__ __forceinline__ void c_st64(u64* p, u64 v) {
  __hip_atomic_store(p, v, __ATOMIC_RELAXED, __HIP_MEMORY_SCOPE_AGENT);
}
__device__ __forceinline__ u32 c_ld32(const u32* p) {
  return __hip_atomic_load((u32*)p, __ATOMIC_RELAXED, __HIP_MEMORY_SCOPE_AGENT);
}
__device__ __forceinline__ u64 c_ld64(const u64* p) {
  return __hip_atomic_load((u64*)p, __ATOMIC_RELAXED, __HIP_MEMORY_SCOPE_AGENT);
}

// ---- grid barrier: no L2 wb-inv. Data moves via coherent ops; the
// workgroup fence inside __syncthreads drains vmcnt so stores are MALL-ack'd
// before the slot store issues. ----
__device__ __forceinline__ void grid_barrier(int* slots, int gen) {
  __syncthreads();
  __threadfence_block();
  if (threadIdx.x == 0)
    __hip_atomic_store(slots + blockIdx.x, gen, __ATOMIC_RELAXED,
                       __HIP_MEMORY_SCOPE_AGENT);
  if (threadIdx.x < 64) {
    for (;;) {
      int v0 = __hip_atomic_load(slots + threadIdx.x,       __ATOMIC_RELAXED, __HIP_MEMORY_SCOPE_AGENT);
      int v1 = __hip_atomic_load(slots + threadIdx.x + 64,  __ATOMIC_RELAXED, __HIP_MEMORY_SCOPE_AGENT);
      int v2 = __hip_atomic_load(slots + threadIdx.x + 128, __ATOMIC_RELAXED, __HIP_MEMORY_SCOPE_AGENT);
      int v3 = __hip_atomic_load(slots + threadIdx.x + 192, __ATOMIC_RELAXED, __HIP_MEMORY_SCOPE_AGENT);
      if (__all((v0 >= gen) && (v1 >= gen) && (v2 >= gen) && (v3 >= gen))) break;
      __builtin_amdgcn_s_sleep(4);
    }
  }
  __syncthreads();
}

// ---------------- fp32 -> bf16 convert ----------------
__global__ __launch_bounds__(256)
void cvt_bf16(const float* __restrict__ src, u16* __restrict__ dst, int n) {
  int i = (blockIdx.x * 256 + threadIdx.x) * 4;
  if (i < n) {
    float4 v = *(const float4*)(src + i);
    dst[i + 0] = f2bf(v.x); dst[i + 1] = f2bf(v.y);
    dst[i + 2] = f2bf(v.z); dst[i + 3] = f2bf(v.w);
  }
}

// ---------------- embedding -> bf16, t-major [T,B,256] ----------------
__global__ __launch_bounds__(64)
void embed_kernel(const int* __restrict__ xw, const float* __restrict__ emb,
                  u16* __restrict__ xe) {
  int bt = blockIdx.x;            // b*T + t
  int b = bt >> 8, t = bt & 255;
  int tok = xw[bt];
  int c = threadIdx.x << 2;
  float4 v = make_float4(0.f, 0.f, 0.f, 0.f);
  if (tok != PADTOK) v = *(const float4*)(emb + (size_t)tok * DEMB + c);
  ushort4 o;
  o.x = f2bf(v.x); o.y = f2bf(v.y); o.z = f2bf(v.z); o.w = f2bf(v.w);
  *(ushort4*)(xe + ((size_t)t * NB + b) * DEMB + c) = o;
}

// ------- GEMM 128x128 tile; COHA: A read via coherent loads (A written by
// this same kernel invocation, e.g. h0); epilogue -> coherent 8B stores ------
template<bool COHA>
__device__ void gemm_tile(const u16* __restrict__ A, long a_rstride,
                          const u16* __restrict__ W, int K,
                          const float* __restrict__ b1, const float* __restrict__ b2,
                          u16* __restrict__ C, long m0, int n0, u16* lds) {
  u16* At = lds;          // [128][32]
  u16* Bt = lds + 4096;   // [128][32]
  int tid = threadIdx.x;
  int w = tid >> 6, l = tid & 63;
  int q = l >> 4, r16 = l & 15;
  int wm = (w & 1) * 64, wn = (w >> 1) * 64;
  faccv acc[4][4] = {};
  int srow = tid >> 1;
  const u16* Ag = A + (m0 + srow) * a_rstride + (tid & 1) * 8;
  const u16* Wg = W + (long)(n0 + srow) * K + (tid & 1) * 8;

  for (int k0 = 0; k0 < K; k0 += 32) {
    __syncthreads();
    if (COHA) {
      const u64* s0 = (const u64*)(Ag + k0);
      const u64* s1 = (const u64*)(Ag + k0 + 16);
      u64* d0 = (u64*)&At[srow * 32 + (tid & 1) * 8];
      u64* d1 = (u64*)&At[srow * 32 + (tid & 1) * 8 + 16];
      d0[0] = c_ld64(s0); d0[1] = c_ld64(s0 + 1);
      d1[0] = c_ld64(s1); d1[1] = c_ld64(s1 + 1);
    } else {
      *(float4*)&At[srow * 32 + (tid & 1) * 8]      = *(const float4*)(Ag + k0);
      *(float4*)&At[srow * 32 + (tid & 1) * 8 + 16] = *(const float4*)(Ag + k0 + 16);
    }
    *(float4*)&Bt[srow * 32 + (tid & 1) * 8]      = *(const float4*)(Wg + k0);
    *(float4*)&Bt[srow * 32 + (tid & 1) * 8 + 16] = *(const float4*)(Wg + k0 + 16);
    __syncthreads();
    bfrag af[4], bf[4];
#pragma unroll
    for (int i = 0; i < 4; ++i) {
      af[i] = *(const bfrag*)&At[(wm + i * 16 + r16) * 32 + q * 8];
      bf[i] = *(const bfrag*)&Bt[(wn + i * 16 + r16) * 32 + q * 8];
    }
#pragma unroll
    for (int mf = 0; mf < 4; ++mf)
#pragma unroll
      for (int nf = 0; nf < 4; ++nf)
        acc[mf][nf] = __builtin_amdgcn_mfma_f32_16x16x32_bf16(af[mf], bf[nf], acc[mf][nf], 0, 0, 0);
  }
  // epilogue: repack via LDS (64 rows x 128 cols) then coherent 8B stores.
  // 256 threads, 4/row, each copies 8 u64 = 32 u16 -> full 128-col row.
  for (int round = 0; round < 2; ++round) {
    __syncthreads();
    if ((w & 1) == round) {
#pragma unroll
      for (int nf = 0; nf < 4; ++nf) {
        int cl = wn + nf * 16 + r16;
        float bs = b1[n0 + cl] + b2[n0 + cl];
#pragma unroll
        for (int mf = 0; mf < 4; ++mf)
#pragma unroll
          for (int r = 0; r < 4; ++r)
            lds[(mf * 16 + q * 4 + r) * 128 + cl] = f2bf(acc[mf][nf][r] + bs);
      }
    }
    __syncthreads();
    int r2 = tid >> 2, seg = tid & 3;
    u64* dst = (u64*)(C + (m0 + round * 64 + r2) * 2048 + n0) + seg * 8;
    const u64* src = (const u64*)(lds + r2 * 128) + seg * 8;
#pragma unroll
    for (int i = 0; i < 8; ++i) c_st64(dst + i, src[i]);
  }
}

// ---------------- persistent kernel ----------------
struct PK {
  const u16 *xe;
  const u16 *w_ih0f, *w_hh0f, *w_ih0r, *w_hh0r;
  const u16 *w_ih1f, *w_hh1f, *w_ih1r;
  const float *bih0f, *bhh0f, *bih0r, *bhh0r, *bih1f, *bhh1f, *bih1r, *bhh1r;
  u16 *xgf, *xgr, *xg1r, *h0;
  u16 *hf0, *hf1, *hr0, *hr1, *h10, *h11;
  int* slots;
};

__global__ __launch_bounds__(256, 1)
void persist_kernel(PK P) {
  __shared__ u16 lds[8320];              // GEMM: 16 KB; scan Ht: 16x520
  const int blk = blockIdx.x, tid = threadIdx.x;
  const int wv = tid >> 6, lane = tid & 63, q = lane >> 4, l16 = lane & 15;
  const size_t XROW = (size_t)NB * DEMB;
  const size_t GROW = (size_t)NB * 2048;
  const size_t HROW = (size_t)NB * 1024;
  int gen = 0;

  const int dir = blk >> 7, b7 = blk & 127;
  const int bn0 = (b7 & 7) * 16;                 // batch group
  const int m0 = (b7 >> 3) * 128 + wv * 32;      // gate base for this wave
  const int bb = bn0 + l16;                      // lane's batch
  const int gg = l16 & 3, ul = l16 >> 2;         // A-row decode
  const int ua0 = (m0 >> 2) + ul;
  const int ua1 = ((m0 + 16) >> 2) + ul;
  const int ub0 = (m0 >> 2) + q;                 // C-operand units
  const int ub1 = ((m0 + 16) >> 2) + q;

  // ================= layer 0 =================
  {
    const u16* whh = dir ? P.w_hh0r : P.w_hh0f;
    u16* hb[2] = { dir ? P.hr0 : P.hf0, dir ? P.hr1 : P.hf1 };
    float cst0 = 0.f, cst1 = 0.f;

    for (int g = 0; g < 8; ++g) {
      for (int t = blk; t < 1024; t += NBLK) {
        bool isr = t >= 512; int tt = t & 511;
        long tm = tt & 31; int tn = tt >> 5;
        const u16* A = P.xe + (size_t)(isr ? (7 - g) : g) * TC * XROW;
        gemm_tile<false>(A, DEMB, isr ? P.w_ih0r : P.w_ih0f, DEMB,
                         isr ? P.bih0r : P.bih0f, isr ? P.bhh0r : P.bhh0f,
                         isr ? P.xgr : P.xgf, tm * 128, tn * 128, lds);
      }
      grid_barrier(P.slots, ++gen);

      // whh slice -> VGPRs (read-only, normal cached loads)
      bfrag wA0[16], wA1[16];
      {
        const u16* w0 = whh + ((size_t)(gg * HH + ua0)) * HH + q * 8;
        const u16* w1 = whh + ((size_t)(gg * HH + ua1)) * HH + q * 8;
#pragma unroll
        for (int kc = 0; kc < 16; ++kc) {
          wA0[kc] = *(const bfrag*)(w0 + kc * 32);
          wA1[kc] = *(const bfrag*)(w1 + kc * 32);
        }
      }

      for (int j = 0; j < 32; ++j) {
        int s = g * 32 + j;
        const u16* h_in = hb[s & 1];
        u16* h_out = hb[(s + 1) & 1];
        const u16* xg_t = dir ? P.xgr + (size_t)(31 - j) * GROW
                              : P.xgf + (size_t)j * GROW;
        // xg coherent loads (dword-granular)
        const u16* xr = xg_t + (size_t)bb * 2048;
        faccv a0, a1;
#pragma unroll
        for (int gi = 0; gi < 4; ++gi) {
          int i0 = gi * HH + ub0, i1 = gi * HH + ub1;
          u32 w0 = c_ld32((const u32*)(xr + (i0 & ~1)));
          u32 w1 = c_ld32((const u32*)(xr + (i1 & ~1)));
          a0[gi] = bf2f((u16)((i0 & 1) ? (w0 >> 16) : (w0 & 0xffff)));
          a1[gi] = bf2f((u16)((i1 & 1) ? (w1 >> 16) : (w1 & 0xffff)));
        }
        // stage h (coherent 8B loads) -> LDS
#pragma unroll
        for (int k = 0; k < 8; ++k) {
          int li = tid + k * 256;
          int row = li >> 7, c8 = li & 127;
          u64 v = c_ld64((const u64*)(h_in + (size_t)(bn0 + row) * HH) + c8);
          *(u64*)&lds[row * 520 + c8 * 4] = v;
        }
        __syncthreads();
#pragma unroll
        for (int kc = 0; kc < 16; ++kc) {
          bfrag bB = *(const bfrag*)&lds[l16 * 520 + kc * 32 + q * 8];
          a0 = __builtin_amdgcn_mfma_f32_16x16x32_bf16(wA0[kc], bB, a0, 0, 0, 0);
          a1 = __builtin_amdgcn_mfma_f32_16x16x32_bf16(wA1[kc], bB, a1, 0, 0, 0);
        }
        float cn0 = sigf(a0[1]) * cst0 + sigf(a0[0]) * tanhf(a0[2]);
        float hn0 = sigf(a0[3]) * tanhf(cn0); cst0 = cn0;
        float cn1 = sigf(a1[1]) * cst1 + sigf(a1[0]) * tanhf(a1[2]);
        float hn1 = sigf(a1[3]) * tanhf(cn1); cst1 = cn1;
        // pack unit-pairs across q-parity -> dword coherent stores
        u32 mine = (u32)f2bf(hn0) | ((u32)f2bf(hn1) << 16);
        u32 other = (u32)__shfl_xor((int)mine, 16);
        if ((q & 1) == 0) {
          u32 p0 = (mine & 0xffffu) | ((other & 0xffffu) << 16);
          u32 p1 = (mine >> 16) | (other & 0xffff0000u);
          c_st32((u32*)(h_out + (size_t)bb * HH + ub0), p0);
          c_st32((u32*)(h_out + (size_t)bb * HH + ub1), p1);
          int tt = dir ? (NT - 1 - s) : s;
          u16* hs = P.h0 + (size_t)tt * HROW + (size_t)bb * 1024 + dir * HH;
          c_st32((u32*)(hs + ub0), p0);
          c_st32((u32*)(hs + ub1), p1);
        }
        grid_barrier(P.slots, ++gen);
      }
    }
  }

  // ================= layer 1 (forward scan; blocks < 128 compute) ==========
  {
    float cst0 = 0.f, cst1 = 0.f;
    u16* hb[2] = { P.h10, P.h11 };

    for (int g = 0; g < 8; ++g) {
      int ntile = (g == 0) ? 528 : 512;
      for (int t = blk; t < ntile; t += NBLK) {
        if (t < 512) {
          long tm = t & 31; int tn = t >> 5;
          gemm_tile<true>(P.h0 + (size_t)g * TC * HROW, 1024, P.w_ih1f, 1024,
                          P.bih1f, P.bhh1f, P.xgf, tm * 128, tn * 128, lds);
        } else {
          int tn = t - 512;
          gemm_tile<true>(P.h0 + (size_t)(NT - 1) * HROW, 1024, P.w_ih1r, 1024,
                          P.bih1r, P.bhh1r, P.xg1r, 0, tn * 128, lds);
        }
      }
      grid_barrier(P.slots, ++gen);

      bfrag wA0[16], wA1[16];
      if (blk < 128) {
        const u16* w0 = P.w_hh1f + ((size_t)(gg * HH + ua0)) * HH + q * 8;
        const u16* w1 = P.w_hh1f + ((size_t)(gg * HH + ua1)) * HH + q * 8;
#pragma unroll
        for (int kc = 0; kc < 16; ++kc) {
          wA0[kc] = *(const bfrag*)(w0 + kc * 32);
          wA1[kc] = *(const bfrag*)(w1 + kc * 32);
        }
      }

      for (int j = 0; j < 32; ++j) {
        if (blk < 128) {
          int s = g * 32 + j;
          const u16* h_in = hb[s & 1];
          u16* h_out = hb[(s + 1) & 1];
          const u16* xr = P.xgf + (size_t)j * GROW + (size_t)bb * 2048;
          faccv a0, a1;
#pragma unroll
          for (int gi = 0; gi < 4; ++gi) {
            int i0 = gi * HH + ub0, i1 = gi * HH + ub1;
            u32 w0 = c_ld32((const u32*)(xr + (i0 & ~1)));
            u32 w1 = c_ld32((const u32*)(xr + (i1 & ~1)));
            a0[gi] = bf2f((u16)((i0 & 1) ? (w0 >> 16) : (w0 & 0xffff)));
            a1[gi] = bf2f((u16)((i1 & 1) ? (w1 >> 16) : (w1 & 0xffff)));
          }
#pragma unroll
          for (int k = 0; k < 8; ++k) {
            int li = tid + k * 256;
            int row = li >> 7, c8 = li & 127;
            u64 v = c_ld64((const u64*)(h_in + (size_t)(bn0 + row) * HH) + c8);
            *(u64*)&lds[row * 520 + c8 * 4] = v;
          }
          __syncthreads();
#pragma unroll
          for (int kc = 0; kc < 16; ++kc) {
            bfrag bB = *(const bfrag*)&lds[l16 * 520 + kc * 32 + q * 8];
            a0 = __builtin_amdgcn_mfma_f32_16x16x32_bf16(wA0[kc], bB, a0, 0, 0, 0);
            a1 = __builtin_amdgcn_mfma_f32_16x16x32_bf16(wA1[kc], bB, a1, 0, 0, 0);
          }
          float cn0 = sigf(a0[1]) * cst0 + sigf(a0[0]) * tanhf(a0[2]);
          float hn0 = sigf(a0[3]) * tanhf(cn0); cst0 = cn0;
          float cn1 = sigf(a1[1]) * cst1 + sigf(a1[0]) * tanhf(a1[2]);
          float hn1 = sigf(a1[3]) * tanhf(cn1); cst1 = cn1;
          u32 mine = (u32)f2bf(hn0) | ((u32)f2bf(hn1) << 16);
          u32 other = (u32)__shfl_xor((int)mine, 16);
          if ((q & 1) == 0) {
            u32 p0 = (mine & 0xffffu) | ((other & 0xffffu) << 16);
            u32 p1 = (mine >> 16) | (other & 0xffff0000u);
            c_st32((u32*)(h_out + (size_t)bb * HH + ub0), p0);
            c_st32((u32*)(h_out + (size_t)bb * HH + ub1), p1);
          }
        }
        grid_barrier(P.slots, ++gen);
      }
    }
  }
}

// ---------------- layer-1 reverse single step (c_prev = h_prev = 0) ------
__global__ __launch_bounds__(512)
void pw_l1r(const u16* __restrict__ xg, u16* __restrict__ h1r) {
  int b = blockIdx.x, u = threadIdx.x;
  float gi = bf2f(xg[(size_t)b * 2048 + u]);
  float gg = bf2f(xg[(size_t)b * 2048 + 2 * HH + u]);
  float go = bf2f(xg[(size_t)b * 2048 + 3 * HH + u]);
  float cn = sigf(gi) * tanhf(gg);
  h1r[(size_t)b * HH + u] = f2bf(sigf(go) * tanhf(cn));
}

// ---------------- classifier ----------------
__global__ __launch_bounds__(128)
void cls_kernel(const u16* __restrict__ hf, const u16* __restrict__ hr,
                const float* __restrict__ wout, const float* __restrict__ bout,
                float* __restrict__ out) {
  int b = blockIdx.x;
  int tid = threadIdx.x;
  float p[NCLS] = {0.f, 0.f, 0.f, 0.f, 0.f};
  for (int j = tid; j < HH; j += 128) {
    float v = bf2f(hf[(size_t)b * HH + j]);
#pragma unroll
    for (int n = 0; n < NCLS; ++n) p[n] += v * wout[n * (2 * HH) + j];
  }
  for (int j = tid; j < HH; j += 128) {
    float v = bf2f(hr[(size_t)b * HH + j]);
#pragma unroll
    for (int n = 0; n < NCLS; ++n) p[n] += v * wout[n * (2 * HH) + HH + j];
  }
  __shared__ float red[NCLS][128];
  for (int n = 0; n < NCLS; ++n) red[n][tid] = p[n];
  __syncthreads();
  for (int s = 64; s > 0; s >>= 1) {
    if (tid < s)
      for (int n = 0; n < NCLS; ++n) red[n][tid] += red[n][tid + s];
    __syncthreads();
  }
  if (tid == 0)
    for (int n = 0; n < NCLS; ++n) out[b * NCLS + n] = red[n][0] + bout[n];
}

// ---------------- host ----------------
extern "C" void kernel_launch(void* const* d_in, const int* in_sizes, int n_in,
                              void* d_out, int out_size, void* d_ws, size_t ws_size,
                              hipStream_t stream) {
  const int*   xw    = (const int*)  d_in[0];
  const float* emb   = (const float*)d_in[1];
  const float* wih0f = (const float*)d_in[2];
  const float* whh0f = (const float*)d_in[3];
  const float* bih0f = (const float*)d_in[4];
  const float* bhh0f = (const float*)d_in[5];
  const float* wih0r = (const float*)d_in[6];
  const float* whh0r = (const float*)d_in[7];
  const float* bih0r = (const float*)d_in[8];
  const float* bhh0r = (const float*)d_in[9];
  const float* wih1f = (const float*)d_in[10];
  const float* whh1f = (const float*)d_in[11];
  const float* bih1f = (const float*)d_in[12];
  const float* bhh1f = (const float*)d_in[13];
  const float* wih1r = (const float*)d_in[14];
  const float* whh1r = (const float*)d_in[15];
  const float* bih1r = (const float*)d_in[16];
  const float* bhh1r = (const float*)d_in[17];
  const float* wout  = (const float*)d_in[18];
  const float* bout  = (const float*)d_in[19];
  float* out = (float*)d_out;
  (void)whh1r; (void)ws_size;

  char* base = (char*)d_ws;
  size_t off = 0;
  auto alloc = [&](size_t bytes) {
    char* p = base + off;
    off += (bytes + 255) & ~(size_t)255;
    return p;
  };
  u16* xe   = (u16*)alloc((size_t)NT * NB * DEMB * 2);
  u16* h0   = (u16*)alloc((size_t)NT * NB * 1024 * 2);
  u16* xgf  = (u16*)alloc((size_t)TC * NB * 2048 * 2);
  u16* xgr  = (u16*)alloc((size_t)TC * NB * 2048 * 2);
  u16* xg1r = (u16*)alloc((size_t)NB * 2048 * 2);
  u16* wb_wih0f = (u16*)alloc(2048 * 256 * 2);
  u16* wb_whh0f = (u16*)alloc(2048 * 512 * 2);
  u16* wb_wih0r = (u16*)alloc(2048 * 256 * 2);
  u16* wb_whh0r = (u16*)alloc(2048 * 512 * 2);
  u16* wb_wih1f = (u16*)alloc(2048 * 1024 * 2);
  u16* wb_wih1r = (u16*)alloc(2048 * 1024 * 2);
  u16* wb_whh1f = (u16*)alloc(2048 * 512 * 2);
  char* stbase = alloc(7 * (size_t)NB * HH * 2 + 1024);
  u16* hf0 = (u16*)stbase;
  u16* hf1 = hf0 + (size_t)NB * HH;
  u16* hr0 = hf1 + (size_t)NB * HH;
  u16* hr1 = hr0 + (size_t)NB * HH;
  u16* h10 = hr1 + (size_t)NB * HH;
  u16* h11 = h10 + (size_t)NB * HH;
  u16* h1r = h11 + (size_t)NB * HH;
  int* slots = (int*)(stbase + 7 * (size_t)NB * HH * 2);

  hipMemsetAsync(stbase, 0, 7 * (size_t)NB * HH * 2 + 1024, stream);

  auto cvt = [&](const float* s, u16* d, int n) {
    cvt_bf16<<<dim3((n / 4 + 255) / 256), dim3(256), 0, stream>>>(s, d, n);
  };
  cvt(wih0f, wb_wih0f, 2048 * 256);
  cvt(whh0f, wb_whh0f, 2048 * 512);
  cvt(wih0r, wb_wih0r, 2048 * 256);
  cvt(whh0r, wb_whh0r, 2048 * 512);
  cvt(wih1f, wb_wih1f, 2048 * 1024);
  cvt(wih1r, wb_wih1r, 2048 * 1024);
  cvt(whh1f, wb_whh1f, 2048 * 512);

  embed_kernel<<<dim3(NB * NT), dim3(64), 0, stream>>>(xw, emb, xe);

  PK P;
  P.xe = xe;
  P.w_ih0f = wb_wih0f; P.w_hh0f = wb_whh0f;
  P.w_ih0r = wb_wih0r; P.w_hh0r = wb_whh0r;
  P.w_ih1f = wb_wih1f; P.w_hh1f = wb_whh1f; P.w_ih1r = wb_wih1r;
  P.bih0f = bih0f; P.bhh0f = bhh0f; P.bih0r = bih0r; P.bhh0r = bhh0r;
  P.bih1f = bih1f; P.bhh1f = bhh1f; P.bih1r = bih1r; P.bhh1r = bhh1r;
  P.xgf = xgf; P.xgr = xgr; P.xg1r = xg1r; P.h0 = h0;
  P.hf0 = hf0; P.hf1 = hf1; P.hr0 = hr0; P.hr1 = hr1; P.h10 = h10; P.h11 = h11;
  P.slots = slots;
  persist_kernel<<<dim3(NBLK), dim3(256), 0, stream>>>(P);

  pw_l1r<<<dim3(NB), dim3(512), 0, stream>>>(xg1r, h1r);
  cls_kernel<<<dim3(NB), dim3(128), 0, stream>>>(h10, h1r, wout, bout, out);
}

// Round 7
// 4007.360 us; speedup vs baseline: 5.7306x; 1.6576x over previous
//
#include <hip/hip_runtime.h>
#include <cmath>

#define NB 128
#define NT 256
#define DEMB 256
#define HH 512
#define NCLS 5
#define PADTOK 29999
#define TC 32          // timestep chunk for xg materialization
#define NBLK 256       // persistent grid (1 block/CU co-resident)

// LDS layout (u16 indices) for scan phase
#define HTOFF 0        // 16 rows x 512, stride 520  -> [0, 8320)
#define XGOFF 8320     // 16 rows x 128, stride 136  -> [8320, 10496)
#define HROFF 10496    // 16 rows x 32              -> [10496, 11008)

typedef __attribute__((ext_vector_type(8))) short bfrag;   // 8 bf16 (4 VGPRs)
typedef __attribute__((ext_vector_type(4))) float faccv;   // 4 fp32 acc
typedef unsigned long long u64;
typedef unsigned int u32;
typedef unsigned short u16;

__device__ __forceinline__ u16 f2bf(float f) {
  union { float f; unsigned u; } v; v.f = f;
  unsigned r = v.u + 0x7fff + ((v.u >> 16) & 1);   // RNE
  return (u16)(r >> 16);
}
__device__ __forceinline__ float bf2f(u16 h) {
  union { unsigned u; float f; } v; v.u = (unsigned)h << 16;
  return v.f;
}
__device__ __forceinline__ float sigf(float x) { return 1.f / (1.f + expf(-x)); }
// fast versions (scan hot path): v_exp_f32 + v_rcp_f32, clamped so no inf/nan
__device__ __forceinline__ float sigf_f(float x) {
  x = fminf(fmaxf(x, -30.f), 30.f);
  float t = __builtin_amdgcn_exp2f(-1.44269504f * x);
  return __builtin_amdgcn_rcpf(1.f + t);
}
__device__ __forceinline__ float tanh_f(float x) {
  x = fminf(fmaxf(x, -15.f), 15.f);
  float t = __builtin_amdgcn_exp2f(2.88539008f * x);
  return (t - 1.f) * __builtin_amdgcn_rcpf(t + 1.f);
}

// ---- coherent (MALL-level) ops: bypass per-XCD L2, NO cache flushes ----
__device__ __forceinline__ void c_st64(u64* p, u64 v) {
  __hip_atomic_store(p, v, __ATOMIC_RELAXED, __HIP_MEMORY_SCOPE_AGENT);
}
__device__ __forceinline__ u64 c_ld64(const u64* p) {
  return __hip_atomic_load((u64*)p, __ATOMIC_RELAXED, __HIP_MEMORY_SCOPE_AGENT);
}

// ---- full grid barrier (chunk boundaries only) ----
__device__ __forceinline__ void grid_barrier(int* slots, int gen) {
  __syncthreads();
  __threadfence_block();
  if (threadIdx.x == 0)
    __hip_atomic_store(slots + blockIdx.x, gen, __ATOMIC_RELAXED,
                       __HIP_MEMORY_SCOPE_AGENT);
  if (threadIdx.x < 64) {
    for (;;) {
      int v0 = __hip_atomic_load(slots + threadIdx.x,       __ATOMIC_RELAXED, __HIP_MEMORY_SCOPE_AGENT);
      int v1 = __hip_atomic_load(slots + threadIdx.x + 64,  __ATOMIC_RELAXED, __HIP_MEMORY_SCOPE_AGENT);
      int v2 = __hip_atomic_load(slots + threadIdx.x + 128, __ATOMIC_RELAXED, __HIP_MEMORY_SCOPE_AGENT);
      int v3 = __hip_atomic_load(slots + threadIdx.x + 192, __ATOMIC_RELAXED, __HIP_MEMORY_SCOPE_AGENT);
      if (__all((v0 >= gen) && (v1 >= gen) && (v2 >= gen) && (v3 >= gen))) break;
      __builtin_amdgcn_s_sleep(2);
    }
  }
  __syncthreads();
}

// ---- 16-block group sync (per scan step): one 64B slot line per group ----
__device__ __forceinline__ void group_sync(int* grp, int mg, int gen) {
  __syncthreads();             // drains vmcnt: coherent stores MALL-ack'd
  __threadfence_block();
  if (threadIdx.x == 0)
    __hip_atomic_store(grp + mg, gen, __ATOMIC_RELAXED, __HIP_MEMORY_SCOPE_AGENT);
  if (threadIdx.x < 64) {
    for (;;) {
      int v = (threadIdx.x < 16)
          ? __hip_atomic_load(grp + threadIdx.x, __ATOMIC_RELAXED, __HIP_MEMORY_SCOPE_AGENT)
          : gen;
      if (__all(v >= gen)) break;
      __builtin_amdgcn_s_sleep(1);
    }
  }
  __syncthreads();
}

// ---------------- fp32 -> bf16 convert ----------------
__global__ __launch_bounds__(256)
void cvt_bf16(const float* __restrict__ src, u16* __restrict__ dst, int n) {
  int i = (blockIdx.x * 256 + threadIdx.x) * 4;
  if (i < n) {
    float4 v = *(const float4*)(src + i);
    dst[i + 0] = f2bf(v.x); dst[i + 1] = f2bf(v.y);
    dst[i + 2] = f2bf(v.z); dst[i + 3] = f2bf(v.w);
  }
}

// ---------------- embedding -> bf16, t-major [T,B,256] ----------------
__global__ __launch_bounds__(64)
void embed_kernel(const int* __restrict__ xw, const float* __restrict__ emb,
                  u16* __restrict__ xe) {
  int bt = blockIdx.x;            // b*T + t
  int b = bt >> 8, t = bt & 255;
  int tok = xw[bt];
  int c = threadIdx.x << 2;
  float4 v = make_float4(0.f, 0.f, 0.f, 0.f);
  if (tok != PADTOK) v = *(const float4*)(emb + (size_t)tok * DEMB + c);
  ushort4 o;
  o.x = f2bf(v.x); o.y = f2bf(v.y); o.z = f2bf(v.z); o.w = f2bf(v.w);
  *(ushort4*)(xe + ((size_t)t * NB + b) * DEMB + c) = o;
}

// ------- GEMM 128x128 tile; COHA: A read via coherent loads; epilogue ->
// coherent full-line stores (8 consecutive u64 per thread) ------
template<bool COHA>
__device__ void gemm_tile(const u16* __restrict__ A, long a_rstride,
                          const u16* __restrict__ W, int K,
                          const float* __restrict__ b1, const float* __restrict__ b2,
                          u16* __restrict__ C, long m0, int n0, u16* lds) {
  u16* At = lds;          // [128][32]
  u16* Bt = lds + 4096;   // [128][32]
  int tid = threadIdx.x;
  int w = tid >> 6, l = tid & 63;
  int q = l >> 4, r16 = l & 15;
  int wm = (w & 1) * 64, wn = (w >> 1) * 64;
  faccv acc[4][4] = {};
  int srow = tid >> 1;
  const u16* Ag = A + (m0 + srow) * a_rstride + (tid & 1) * 8;
  const u16* Wg = W + (long)(n0 + srow) * K + (tid & 1) * 8;

  for (int k0 = 0; k0 < K; k0 += 32) {
    __syncthreads();
    if (COHA) {
      const u64* s0 = (const u64*)(Ag + k0);
      const u64* s1 = (const u64*)(Ag + k0 + 16);
      u64* d0 = (u64*)&At[srow * 32 + (tid & 1) * 8];
      u64* d1 = (u64*)&At[srow * 32 + (tid & 1) * 8 + 16];
      d0[0] = c_ld64(s0); d0[1] = c_ld64(s0 + 1);
      d1[0] = c_ld64(s1); d1[1] = c_ld64(s1 + 1);
    } else {
      *(float4*)&At[srow * 32 + (tid & 1) * 8]      = *(const float4*)(Ag + k0);
      *(float4*)&At[srow * 32 + (tid & 1) * 8 + 16] = *(const float4*)(Ag + k0 + 16);
    }
    *(float4*)&Bt[srow * 32 + (tid & 1) * 8]      = *(const float4*)(Wg + k0);
    *(float4*)&Bt[srow * 32 + (tid & 1) * 8 + 16] = *(const float4*)(Wg + k0 + 16);
    __syncthreads();
    bfrag af[4], bf[4];
#pragma unroll
    for (int i = 0; i < 4; ++i) {
      af[i] = *(const bfrag*)&At[(wm + i * 16 + r16) * 32 + q * 8];
      bf[i] = *(const bfrag*)&Bt[(wn + i * 16 + r16) * 32 + q * 8];
    }
#pragma unroll
    for (int mf = 0; mf < 4; ++mf)
#pragma unroll
      for (int nf = 0; nf < 4; ++nf)
        acc[mf][nf] = __builtin_amdgcn_mfma_f32_16x16x32_bf16(af[mf], bf[nf], acc[mf][nf], 0, 0, 0);
  }
  // epilogue: repack via LDS (64 rows x 128 cols) then coherent stores
  for (int round = 0; round < 2; ++round) {
    __syncthreads();
    if ((w & 1) == round) {
#pragma unroll
      for (int nf = 0; nf < 4; ++nf) {
        int cl = wn + nf * 16 + r16;
        float bs = b1[n0 + cl] + b2[n0 + cl];
#pragma unroll
        for (int mf = 0; mf < 4; ++mf)
#pragma unroll
          for (int r = 0; r < 4; ++r)
            lds[(mf * 16 + q * 4 + r) * 128 + cl] = f2bf(acc[mf][nf][r] + bs);
      }
    }
    __syncthreads();
    int r2 = tid >> 2, seg = tid & 3;
    u64* dst = (u64*)(C + (m0 + round * 64 + r2) * 2048 + n0) + seg * 8;
    const u64* src = (const u64*)(lds + r2 * 128) + seg * 8;
#pragma unroll
    for (int i = 0; i < 8; ++i) c_st64(dst + i, src[i]);
  }
}

// ---------------- persistent kernel ----------------
struct PK {
  const u16 *xe;
  const u16 *w_ih0f, *w_hh0f, *w_ih0r, *w_hh0r;
  const u16 *w_ih1f, *w_hh1f, *w_ih1r;
  const float *bih0f, *bhh0f, *bih0r, *bhh0r, *bih1f, *bhh1f, *bih1r, *bhh1r;
  u16 *xgf, *xgr, *xg1r, *h0;
  u16 *hf0, *hf1, *hr0, *hr1, *h10, *h11;
  int* slots;            // [0,256): grid; [256,512): 16 groups x 16
};

__global__ __launch_bounds__(256, 1)
void persist_kernel(PK P) {
  __shared__ u16 lds[11008];             // 22 KB (GEMM uses first 16 KB)
  const int blk = blockIdx.x, tid = threadIdx.x;
  const int wv = tid >> 6, lane = tid & 63, q = lane >> 4, l16 = lane & 15;
  const size_t XROW = (size_t)NB * DEMB;
  const size_t GROW = (size_t)NB * 2048;
  const size_t HROW = (size_t)NB * 1024;
  int ggen = 0, sgen = 0;

  const int dir = blk >> 7, b7 = blk & 127;
  const int bg = b7 & 7, mg = b7 >> 3;
  const int bn0 = bg * 16;                       // batch group base
  const int m0 = mg * 128 + wv * 32;             // gate base for this wave
  const int gg = l16 & 3, ul = l16 >> 2;         // A-row decode
  const int ua0 = (m0 >> 2) + ul;
  const int ua1 = ((m0 + 16) >> 2) + ul;
  const int ulq = wv * 8 + q;                    // block-local C unit (0..31)
  int* gslots = P.slots;
  int* grp = P.slots + 256 + (dir * 8 + bg) * 16;

  // ================= layer 0 =================
  {
    const u16* whh = dir ? P.w_hh0r : P.w_hh0f;
    u16* hb[2] = { dir ? P.hr0 : P.hf0, dir ? P.hr1 : P.hf1 };
    float cst0 = 0.f, cst1 = 0.f;

    for (int g = 0; g < 8; ++g) {
      for (int t = blk; t < 1024; t += NBLK) {
        bool isr = t >= 512; int tt = t & 511;
        long tm = tt & 31; int tn = tt >> 5;
        const u16* A = P.xe + (size_t)(isr ? (7 - g) : g) * TC * XROW;
        gemm_tile<false>(A, DEMB, isr ? P.w_ih0r : P.w_ih0f, DEMB,
                         isr ? P.bih0r : P.bih0f, isr ? P.bhh0r : P.bhh0f,
                         isr ? P.xgr : P.xgf, tm * 128, tn * 128, lds);
      }
      grid_barrier(gslots, ++ggen);

      // whh slice -> VGPRs (read-only, normal cached loads)
      bfrag wA0[16], wA1[16];
      {
        const u16* w0 = whh + ((size_t)(gg * HH + ua0)) * HH + q * 8;
        const u16* w1 = whh + ((size_t)(gg * HH + ua1)) * HH + q * 8;
#pragma unroll
        for (int kc = 0; kc < 16; ++kc) {
          wA0[kc] = *(const bfrag*)(w0 + kc * 32);
          wA1[kc] = *(const bfrag*)(w1 + kc * 32);
        }
      }

      for (int j = 0; j < 32; ++j) {
        int s = g * 32 + j;
        const u16* h_in = hb[s & 1];
        u16* h_out = hb[(s + 1) & 1];
        const u16* xg_t = dir ? P.xgr + (size_t)(31 - j) * GROW
                              : P.xgf + (size_t)j * GROW;
        // stage xg tile (coalesced coherent u64): 16b x 4g x 8 u64
        const u64* xg64 = (const u64*)xg_t;
#pragma unroll
        for (int k = 0; k < 2; ++k) {
          int li = tid + k * 256;
          int b = li >> 5, gs = (li >> 3) & 3, jj = li & 7;
          u64 v = c_ld64(xg64 + (size_t)(bn0 + b) * 512 + gs * 128 + mg * 8 + jj);
          *(u64*)&lds[XGOFF + b * 136 + (gs * 8 + jj) * 4] = v;
        }
        // stage h (coalesced coherent u64) -> Ht
#pragma unroll
        for (int k = 0; k < 8; ++k) {
          int li = tid + k * 256;
          int row = li >> 7, c8 = li & 127;
          u64 v = c_ld64((const u64*)(h_in + (size_t)(bn0 + row) * HH) + c8);
          *(u64*)&lds[HTOFF + row * 520 + c8 * 4] = v;
        }
        __syncthreads();
        faccv a0, a1;
#pragma unroll
        for (int gi = 0; gi < 4; ++gi) {
          a0[gi] = bf2f(lds[XGOFF + l16 * 136 + gi * 32 + ulq]);
          a1[gi] = bf2f(lds[XGOFF + l16 * 136 + gi * 32 + ulq + 4]);
        }
#pragma unroll
        for (int kc = 0; kc < 16; ++kc) {
          bfrag bB = *(const bfrag*)&lds[HTOFF + l16 * 520 + kc * 32 + q * 8];
          a0 = __builtin_amdgcn_mfma_f32_16x16x32_bf16(wA0[kc], bB, a0, 0, 0, 0);
          a1 = __builtin_amdgcn_mfma_f32_16x16x32_bf16(wA1[kc], bB, a1, 0, 0, 0);
        }
        float cn0 = sigf_f(a0[1]) * cst0 + sigf_f(a0[0]) * tanh_f(a0[2]);
        float hn0 = sigf_f(a0[3]) * tanh_f(cn0); cst0 = cn0;
        float cn1 = sigf_f(a1[1]) * cst1 + sigf_f(a1[0]) * tanh_f(a1[2]);
        float hn1 = sigf_f(a1[3]) * tanh_f(cn1); cst1 = cn1;
        // repack h through LDS -> full-line coherent stores
        lds[HROFF + l16 * 32 + ulq]     = f2bf(hn0);
        lds[HROFF + l16 * 32 + ulq + 4] = f2bf(hn1);
        __syncthreads();
        if (tid < 128) {
          int row = tid >> 3, jj = tid & 7;
          u64 v = *(const u64*)&lds[HROFF + row * 32 + jj * 4];
          c_st64((u64*)(h_out + (size_t)(bn0 + row) * HH) + mg * 8 + jj, v);
          int tt = dir ? (NT - 1 - s) : s;
          c_st64((u64*)(P.h0 + (size_t)tt * HROW) +
                     (size_t)(bn0 + row) * 256 + dir * 128 + mg * 8 + jj, v);
        }
        group_sync(grp, mg, ++sgen);
      }
    }
  }

  // ================= layer 1 (forward scan; blocks < 128 compute) ==========
  {
    float cst0 = 0.f, cst1 = 0.f;
    u16* hb[2] = { P.h10, P.h11 };

    for (int g = 0; g < 8; ++g) {
      int ntile = (g == 0) ? 528 : 512;
      for (int t = blk; t < ntile; t += NBLK) {
        if (t < 512) {
          long tm = t & 31; int tn = t >> 5;
          gemm_tile<true>(P.h0 + (size_t)g * TC * HROW, 1024, P.w_ih1f, 1024,
                          P.bih1f, P.bhh1f, P.xgf, tm * 128, tn * 128, lds);
        } else {
          int tn = t - 512;
          gemm_tile<true>(P.h0 + (size_t)(NT - 1) * HROW, 1024, P.w_ih1r, 1024,
                          P.bih1r, P.bhh1r, P.xg1r, 0, tn * 128, lds);
        }
      }
      grid_barrier(gslots, ++ggen);

      if (blk < 128) {
        bfrag wA0[16], wA1[16];
        {
          const u16* w0 = P.w_hh1f + ((size_t)(gg * HH + ua0)) * HH + q * 8;
          const u16* w1 = P.w_hh1f + ((size_t)(gg * HH + ua1)) * HH + q * 8;
#pragma unroll
          for (int kc = 0; kc < 16; ++kc) {
            wA0[kc] = *(const bfrag*)(w0 + kc * 32);
            wA1[kc] = *(const bfrag*)(w1 + kc * 32);
          }
        }
        for (int j = 0; j < 32; ++j) {
          int s = g * 32 + j;
          const u16* h_in = hb[s & 1];
          u16* h_out = hb[(s + 1) & 1];
          const u64* xg64 = (const u64*)(P.xgf + (size_t)j * GROW);
#pragma unroll
          for (int k = 0; k < 2; ++k) {
            int li = tid + k * 256;
            int b = li >> 5, gs = (li >> 3) & 3, jj = li & 7;
            u64 v = c_ld64(xg64 + (size_t)(bn0 + b) * 512 + gs * 128 + mg * 8 + jj);
            *(u64*)&lds[XGOFF + b * 136 + (gs * 8 + jj) * 4] = v;
          }
#pragma unroll
          for (int k = 0; k < 8; ++k) {
            int li = tid + k * 256;
            int row = li >> 7, c8 = li & 127;
            u64 v = c_ld64((const u64*)(h_in + (size_t)(bn0 + row) * HH) + c8);
            *(u64*)&lds[HTOFF + row * 520 + c8 * 4] = v;
          }
          __syncthreads();
          faccv a0, a1;
#pragma unroll
          for (int gi = 0; gi < 4; ++gi) {
            a0[gi] = bf2f(lds[XGOFF + l16 * 136 + gi * 32 + ulq]);
            a1[gi] = bf2f(lds[XGOFF + l16 * 136 + gi * 32 + ulq + 4]);
          }
#pragma unroll
          for (int kc = 0; kc < 16; ++kc) {
            bfrag bB = *(const bfrag*)&lds[HTOFF + l16 * 520 + kc * 32 + q * 8];
            a0 = __builtin_amdgcn_mfma_f32_16x16x32_bf16(wA0[kc], bB, a0, 0, 0, 0);
            a1 = __builtin_amdgcn_mfma_f32_16x16x32_bf16(wA1[kc], bB, a1, 0, 0, 0);
          }
          float cn0 = sigf_f(a0[1]) * cst0 + sigf_f(a0[0]) * tanh_f(a0[2]);
          float hn0 = sigf_f(a0[3]) * tanh_f(cn0); cst0 = cn0;
          float cn1 = sigf_f(a1[1]) * cst1 + sigf_f(a1[0]) * tanh_f(a1[2]);
          float hn1 = sigf_f(a1[3]) * tanh_f(cn1); cst1 = cn1;
          lds[HROFF + l16 * 32 + ulq]     = f2bf(hn0);
          lds[HROFF + l16 * 32 + ulq + 4] = f2bf(hn1);
          __syncthreads();
          if (tid < 128) {
            int row = tid >> 3, jj = tid & 7;
            u64 v = *(const u64*)&lds[HROFF + row * 32 + jj * 4];
            c_st64((u64*)(h_out + (size_t)(bn0 + row) * HH) + mg * 8 + jj, v);
          }
          group_sync(grp, mg, ++sgen);
        }
      }
      grid_barrier(gslots, ++ggen);   // protect xgf before next chunk's GEMM
    }
  }
}

// ---------------- layer-1 reverse single step (c_prev = h_prev = 0) ------
__global__ __launch_bounds__(512)
void pw_l1r(const u16* __restrict__ xg, u16* __restrict__ h1r) {
  int b = blockIdx.x, u = threadIdx.x;
  float gi = bf2f(xg[(size_t)b * 2048 + u]);
  float gg = bf2f(xg[(size_t)b * 2048 + 2 * HH + u]);
  float go = bf2f(xg[(size_t)b * 2048 + 3 * HH + u]);
  float cn = sigf(gi) * tanhf(gg);
  h1r[(size_t)b * HH + u] = f2bf(sigf(go) * tanhf(cn));
}

// ---------------- classifier ----------------
__global__ __launch_bounds__(128)
void cls_kernel(const u16* __restrict__ hf, const u16* __restrict__ hr,
                const float* __restrict__ wout, const float* __restrict__ bout,
                float* __restrict__ out) {
  int b = blockIdx.x;
  int tid = threadIdx.x;
  float p[NCLS] = {0.f, 0.f, 0.f, 0.f, 0.f};
  for (int j = tid; j < HH; j += 128) {
    float v = bf2f(hf[(size_t)b * HH + j]);
#pragma unroll
    for (int n = 0; n < NCLS; ++n) p[n] += v * wout[n * (2 * HH) + j];
  }
  for (int j = tid; j < HH; j += 128) {
    float v = bf2f(hr[(size_t)b * HH + j]);
#pragma unroll
    for (int n = 0; n < NCLS; ++n) p[n] += v * wout[n * (2 * HH) + HH + j];
  }
  __shared__ float red[NCLS][128];
  for (int n = 0; n < NCLS; ++n) red[n][tid] = p[n];
  __syncthreads();
  for (int s = 64; s > 0; s >>= 1) {
    if (tid < s)
      for (int n = 0; n < NCLS; ++n) red[n][tid] += red[n][tid + s];
    __syncthreads();
  }
  if (tid == 0)
    for (int n = 0; n < NCLS; ++n) out[b * NCLS + n] = red[n][0] + bout[n];
}

// ---------------- host ----------------
extern "C" void kernel_launch(void* const* d_in, const int* in_sizes, int n_in,
                              void* d_out, int out_size, void* d_ws, size_t ws_size,
                              hipStream_t stream) {
  const int*   xw    = (const int*)  d_in[0];
  const float* emb   = (const float*)d_in[1];
  const float* wih0f = (const float*)d_in[2];
  const float* whh0f = (const float*)d_in[3];
  const float* bih0f = (const float*)d_in[4];
  const float* bhh0f = (const float*)d_in[5];
  const float* wih0r = (const float*)d_in[6];
  const float* whh0r = (const float*)d_in[7];
  const float* bih0r = (const float*)d_in[8];
  const float* bhh0r = (const float*)d_in[9];
  const float* wih1f = (const float*)d_in[10];
  const float* whh1f = (const float*)d_in[11];
  const float* bih1f = (const float*)d_in[12];
  const float* bhh1f = (const float*)d_in[13];
  const float* wih1r = (const float*)d_in[14];
  const float* whh1r = (const float*)d_in[15];
  const float* bih1r = (const float*)d_in[16];
  const float* bhh1r = (const float*)d_in[17];
  const float* wout  = (const float*)d_in[18];
  const float* bout  = (const float*)d_in[19];
  float* out = (float*)d_out;
  (void)whh1r; (void)ws_size;

  char* base = (char*)d_ws;
  size_t off = 0;
  auto alloc = [&](size_t bytes) {
    char* p = base + off;
    off += (bytes + 255) & ~(size_t)255;
    return p;
  };
  u16* xe   = (u16*)alloc((size_t)NT * NB * DEMB * 2);
  u16* h0   = (u16*)alloc((size_t)NT * NB * 1024 * 2);
  u16* xgf  = (u16*)alloc((size_t)TC * NB * 2048 * 2);
  u16* xgr  = (u16*)alloc((size_t)TC * NB * 2048 * 2);
  u16* xg1r = (u16*)alloc((size_t)NB * 2048 * 2);
  u16* wb_wih0f = (u16*)alloc(2048 * 256 * 2);
  u16* wb_whh0f = (u16*)alloc(2048 * 512 * 2);
  u16* wb_wih0r = (u16*)alloc(2048 * 256 * 2);
  u16* wb_whh0r = (u16*)alloc(2048 * 512 * 2);
  u16* wb_wih1f = (u16*)alloc(2048 * 1024 * 2);
  u16* wb_wih1r = (u16*)alloc(2048 * 1024 * 2);
  u16* wb_whh1f = (u16*)alloc(2048 * 512 * 2);
  char* stbase = alloc(7 * (size_t)NB * HH * 2 + 2048);
  u16* hf0 = (u16*)stbase;
  u16* hf1 = hf0 + (size_t)NB * HH;
  u16* hr0 = hf1 + (size_t)NB * HH;
  u16* hr1 = hr0 + (size_t)NB * HH;
  u16* h10 = hr1 + (size_t)NB * HH;
  u16* h11 = h10 + (size_t)NB * HH;
  u16* h1r = h11 + (size_t)NB * HH;
  int* slots = (int*)(stbase + 7 * (size_t)NB * HH * 2);

  hipMemsetAsync(stbase, 0, 7 * (size_t)NB * HH * 2 + 2048, stream);

  auto cvt = [&](const float* s, u16* d, int n) {
    cvt_bf16<<<dim3((n / 4 + 255) / 256), dim3(256), 0, stream>>>(s, d, n);
  };
  cvt(wih0f, wb_wih0f, 2048 * 256);
  cvt(whh0f, wb_whh0f, 2048 * 512);
  cvt(wih0r, wb_wih0r, 2048 * 256);
  cvt(whh0r, wb_whh0r, 2048 * 512);
  cvt(wih1f, wb_wih1f, 2048 * 1024);
  cvt(wih1r, wb_wih1r, 2048 * 1024);
  cvt(whh1f, wb_whh1f, 2048 * 512);

  embed_kernel<<<dim3(NB * NT), dim3(64), 0, stream>>>(xw, emb, xe);

  PK P;
  P.xe = xe;
  P.w_ih0f = wb_wih0f; P.w_hh0f = wb_whh0f;
  P.w_ih0r = wb_wih0r; P.w_hh0r = wb_whh0r;
  P.w_ih1f = wb_wih1f; P.w_hh1f = wb_whh1f; P.w_ih1r = wb_wih1r;
  P.bih0f = bih0f; P.bhh0f = bhh0f; P.bih0r = bih0r; P.bhh0r = bhh0r;
  P.bih1f = bih1f; P.bhh1f = bhh1f; P.bih1r = bih1r; P.bhh1r = bhh1r;
  P.xgf = xgf; P.xgr = xgr; P.xg1r = xg1r; P.h0 = h0;
  P.hf0 = hf0; P.hf1 = hf1; P.hr0 = hr0; P.hr1 = hr1; P.h10 = h10; P.h11 = h11;
  P.slots = slots;
  persist_kernel<<<dim3(NBLK), dim3(256), 0, stream>>>(P);

  pw_l1r<<<dim3(NB), dim3(512), 0, stream>>>(xg1r, h1r);
  cls_kernel<<<dim3(NB), dim3(128), 0, stream>>>(h10, h1r, wout, bout, out);
}